// Round 5
// baseline (1061.484 us; speedup 1.0000x reference)
//
#include <hip/hip_runtime.h>
#include <stdint.h>

typedef unsigned short u16;
typedef __attribute__((ext_vector_type(8))) __bf16 bf16x8;
typedef __attribute__((ext_vector_type(4))) float f32x4;

#define T_SEQ 2048
#define CDIM 1024
#define NH 16
#define HD 64
#define NTOK 4096
#define EPS_RMS 1.1920929e-07f
#define LDKs 72
#define BSWZ(n, kk) ((kk) ^ ((((n) >> 2) & 7) << 3))

__device__ __forceinline__ u16 f2bf(float x) {
  union { float f; uint32_t u; } v; v.f = x;
  uint32_t r = v.u + 0x7fffu + ((v.u >> 16) & 1u);
  return (u16)(r >> 16);
}
__device__ __forceinline__ float bf2f(u16 h) {
  union { uint32_t u; float f; } v; v.u = ((uint32_t)h) << 16; return v.f;
}
__device__ __forceinline__ bf16x8 ld8(const u16* p) {
  uint4 q = *(const uint4*)p;
  return __builtin_bit_cast(bf16x8, q);
}
#define MFMA16(a, b, c) __builtin_amdgcn_mfma_f32_16x16x32_bf16((a), (b), (c), 0, 0, 0)

// ---- rope table
__global__ __launch_bounds__(256) void rope_table_k(float* __restrict__ cosT, float* __restrict__ sinT) {
  int idx = blockIdx.x * 256 + threadIdx.x;   // T*32
  int t = idx >> 5, d = idx & 31;
  float inv = 1.0f / powf(10000.0f, (float)(2 * d) / 64.0f);
  float a = (float)t * inv;
  cosT[idx] = cosf(a);
  sinT[idx] = sinf(a);
}

// ---- rmsnorm fp32 out
__global__ __launch_bounds__(256) void rmsnorm_f_k(const float* __restrict__ x, float* __restrict__ hf) {
  int row = blockIdx.x;
  const float* xr = x + (size_t)row * CDIM;
  int tid = threadIdx.x;
  float v[4]; float s = 0.f;
  for (int i = 0; i < 4; ++i) { v[i] = xr[tid + 256 * i]; s += v[i] * v[i]; }
  for (int off = 32; off >= 1; off >>= 1) s += __shfl_xor(s, off);
  __shared__ float red[4];
  int w = tid >> 6, lane = tid & 63;
  if (lane == 0) red[w] = s;
  __syncthreads();
  s = red[0] + red[1] + red[2] + red[3];
  float rs = 1.0f / sqrtf(s * (1.f / CDIM) + EPS_RMS);
  for (int i = 0; i < 4; ++i) hf[(size_t)row * CDIM + tid + 256 * i] = v[i] * rs;
}

// ---- rmsnorm bf16 out
__global__ __launch_bounds__(256) void rmsnorm_b_k(const float* __restrict__ x, u16* __restrict__ hb) {
  int row = blockIdx.x;
  const float* xr = x + (size_t)row * CDIM;
  int tid = threadIdx.x;
  float v[4]; float s = 0.f;
  for (int i = 0; i < 4; ++i) { v[i] = xr[tid + 256 * i]; s += v[i] * v[i]; }
  for (int off = 32; off >= 1; off >>= 1) s += __shfl_xor(s, off);
  __shared__ float red[4];
  int w = tid >> 6, lane = tid & 63;
  if (lane == 0) red[w] = s;
  __syncthreads();
  s = red[0] + red[1] + red[2] + red[3];
  float rs = 1.0f / sqrtf(s * (1.f / CDIM) + EPS_RMS);
  for (int i = 0; i < 4; ++i) hb[(size_t)row * CDIM + tid + 256 * i] = f2bf(v[i] * rs);
}

// ---- split-precision GEMM: C = A(fp32 4096x1024) * B(fp32 1024x1024, k-major)
// A,B split to bf16 hi/lo on the fly; 3-product Ootomo accumulate in fp32 MFMA.
// EPI 0: per-head RMS + rope + split -> outH/outL at (b,h,t,d)
// EPI 1: split -> outH/outL at (b,t,c)
// EPI 2: outF = Xadd + acc (fp32)
template <int EPI>
__global__ __launch_bounds__(256) void gemm_split_k(const float* __restrict__ A, const float* __restrict__ B,
                                                    const float* __restrict__ Xadd, float* __restrict__ outF,
                                                    u16* __restrict__ outH, u16* __restrict__ outL,
                                                    const float* __restrict__ cosT, const float* __restrict__ sinT) {
  const int N = CDIM, K = CDIM;
  __shared__ __align__(16) u16 Ah[128][LDKs];
  __shared__ __align__(16) u16 Al[128][LDKs];
  __shared__ __align__(16) u16 Bh[128][LDKs];
  __shared__ __align__(16) u16 Bl[128][LDKs];
  int m0 = blockIdx.y * 128, n0 = blockIdx.x * 128;
  int tid = threadIdx.x, lane = tid & 63, w = tid >> 6;
  int wr = w >> 1, wc = w & 1;
  int fr = lane & 15, fq = lane >> 4, kof = fq * 8;
  f32x4 acc[4][4] = {};
  for (int kt = 0; kt < K; kt += 64) {
    // A stage: 128 rows x 64 k fp32, split inline
    #pragma unroll
    for (int i = 0; i < 8; ++i) {
      int slot = tid + i * 256;
      int r = slot >> 4, q = slot & 15;
      float4 v = *(const float4*)(A + (size_t)(m0 + r) * K + kt + q * 4);
      ushort4 hi, lo;
      hi.x = f2bf(v.x); lo.x = f2bf(v.x - bf2f(hi.x));
      hi.y = f2bf(v.y); lo.y = f2bf(v.y - bf2f(hi.y));
      hi.z = f2bf(v.z); lo.z = f2bf(v.z - bf2f(hi.z));
      hi.w = f2bf(v.w); lo.w = f2bf(v.w - bf2f(hi.w));
      *(ushort4*)&Ah[r][q * 4] = hi;
      *(ushort4*)&Al[r][q * 4] = lo;
    }
    // B stage: 64 k x 128 n fp32, register 4x4 transpose, swizzled LDS
    #pragma unroll
    for (int i = 0; i < 2; ++i) {
      int sub = tid + i * 256;          // 0..511
      int nb = (sub & 31) * 4;
      int kk0 = (sub >> 5) * 4;
      float4 r0 = *(const float4*)(B + (size_t)(kt + kk0 + 0) * N + n0 + nb);
      float4 r1 = *(const float4*)(B + (size_t)(kt + kk0 + 1) * N + n0 + nb);
      float4 r2 = *(const float4*)(B + (size_t)(kt + kk0 + 2) * N + n0 + nb);
      float4 r3 = *(const float4*)(B + (size_t)(kt + kk0 + 3) * N + n0 + nb);
      float cv[4][4] = {{r0.x, r1.x, r2.x, r3.x}, {r0.y, r1.y, r2.y, r3.y},
                        {r0.z, r1.z, r2.z, r3.z}, {r0.w, r1.w, r2.w, r3.w}};
      #pragma unroll
      for (int c = 0; c < 4; ++c) {
        int n = nb + c;
        int kp = BSWZ(n, kk0);
        ushort4 hi, lo;
        hi.x = f2bf(cv[c][0]); lo.x = f2bf(cv[c][0] - bf2f(hi.x));
        hi.y = f2bf(cv[c][1]); lo.y = f2bf(cv[c][1] - bf2f(hi.y));
        hi.z = f2bf(cv[c][2]); lo.z = f2bf(cv[c][2] - bf2f(hi.z));
        hi.w = f2bf(cv[c][3]); lo.w = f2bf(cv[c][3] - bf2f(hi.w));
        *(ushort4*)&Bh[n][kp] = hi;
        *(ushort4*)&Bl[n][kp] = lo;
      }
    }
    __syncthreads();
    #pragma unroll
    for (int ks = 0; ks < 2; ++ks) {
      int kk = ks * 32 + kof;
      bf16x8 ah[4], al[4], bh4[4], bl4[4];
      #pragma unroll
      for (int i = 0; i < 4; ++i) {
        ah[i] = ld8(&Ah[wr * 64 + i * 16 + fr][kk]);
        al[i] = ld8(&Al[wr * 64 + i * 16 + fr][kk]);
      }
      #pragma unroll
      for (int j = 0; j < 4; ++j) {
        int n = wc * 64 + j * 16 + fr;
        bh4[j] = ld8(&Bh[n][BSWZ(n, kk)]);
        bl4[j] = ld8(&Bl[n][BSWZ(n, kk)]);
      }
      #pragma unroll
      for (int i = 0; i < 4; ++i)
        #pragma unroll
        for (int j = 0; j < 4; ++j) {
          acc[i][j] = MFMA16(al[i], bh4[j], acc[i][j]);
          acc[i][j] = MFMA16(ah[i], bl4[j], acc[i][j]);
          acc[i][j] = MFMA16(ah[i], bh4[j], acc[i][j]);
        }
    }
    __syncthreads();
  }
  if (EPI == 0) {
    // per-head RMS over D=64 (this wave's 64 cols = one full head) + rope + split store
    int h = (n0 + wc * 64) >> 6;
    #pragma unroll
    for (int i = 0; i < 4; ++i) {
      #pragma unroll
      for (int j = 0; j < 4; ++j) {
        int row = m0 + wr * 64 + i * 16 + fq * 4 + j;
        float v0 = acc[i][0][j], v1 = acc[i][1][j], v2 = acc[i][2][j], v3 = acc[i][3][j];
        float ss = v0 * v0 + v1 * v1 + v2 * v2 + v3 * v3;
        ss += __shfl_xor(ss, 1); ss += __shfl_xor(ss, 2);
        ss += __shfl_xor(ss, 4); ss += __shfl_xor(ss, 8);
        float rs = 1.0f / sqrtf(ss * (1.f / HD) + EPS_RMS);
        float x0 = v0 * rs, x1 = v1 * rs, x2 = v2 * rs, x3 = v3 * rs;
        int t = row & (T_SEQ - 1), b = row >> 11;
        float c0 = cosT[t * 32 + fr],      s0 = sinT[t * 32 + fr];
        float c1 = cosT[t * 32 + fr + 16], s1 = sinT[t * 32 + fr + 16];
        float o0 = x0 * c0 + x2 * s0;
        float o1 = x1 * c1 + x3 * s1;
        float o2 = x2 * c0 - x0 * s0;
        float o3 = x3 * c1 - x1 * s1;
        size_t base = ((size_t)(b * NH + h) * T_SEQ + t) * HD + fr;
        u16 hh;
        hh = f2bf(o0); outH[base]      = hh; outL[base]      = f2bf(o0 - bf2f(hh));
        hh = f2bf(o1); outH[base + 16] = hh; outL[base + 16] = f2bf(o1 - bf2f(hh));
        hh = f2bf(o2); outH[base + 32] = hh; outL[base + 32] = f2bf(o2 - bf2f(hh));
        hh = f2bf(o3); outH[base + 48] = hh; outL[base + 48] = f2bf(o3 - bf2f(hh));
      }
    }
  } else {
    #pragma unroll
    for (int i = 0; i < 4; ++i)
      #pragma unroll
      for (int j = 0; j < 4; ++j) {
        int row = m0 + wr * 64 + i * 16 + fq * 4 + j;
        #pragma unroll
        for (int jf = 0; jf < 4; ++jf) {
          int gn = n0 + wc * 64 + jf * 16 + fr;
          float v = acc[i][jf][j];
          if (EPI == 1) {
            u16 hh = f2bf(v);
            outH[(size_t)row * CDIM + gn] = hh;
            outL[(size_t)row * CDIM + gn] = f2bf(v - bf2f(hh));
          } else {
            outF[(size_t)row * CDIM + gn] = Xadd[(size_t)row * CDIM + gn] + v;
          }
        }
      }
  }
}

// ---- transpose v (bf16): (b,t,h,d) -> (b,h,d,t); z selects hi/lo
__global__ __launch_bounds__(256) void vtrans_k(const u16* __restrict__ vhp, const u16* __restrict__ vlp,
                                                u16* __restrict__ vthp, u16* __restrict__ vtlp) {
  const u16* src = blockIdx.z ? vlp : vhp;
  u16* dst = blockIdx.z ? vtlp : vthp;
  __shared__ u16 t_[64][65];
  int bh = blockIdx.y, b = bh >> 4, h = bh & 15;
  int t0 = blockIdx.x * 64;
  const u16* in = src + ((size_t)b * T_SEQ) * CDIM + (size_t)h * HD;
  u16* out = dst + (size_t)bh * HD * T_SEQ;
  int tx = threadIdx.x & 63, ty = threadIdx.x >> 6;
  for (int i = ty; i < 64; i += 4) t_[i][tx] = in[(size_t)(t0 + i) * CDIM + tx];
  __syncthreads();
  for (int i = ty; i < 64; i += 4) out[(size_t)i * T_SEQ + t0 + tx] = t_[tx][i];
}

// ---- flash attention (split precision), 1 wave / 32 q-rows, KV blocks of 32
__global__ __launch_bounds__(64) void attn_k(const u16* __restrict__ qhp, const u16* __restrict__ qlp,
                                             const u16* __restrict__ khp, const u16* __restrict__ klp,
                                             const u16* __restrict__ vth, const u16* __restrict__ vtl,
                                             float* __restrict__ y) {
  int bh = blockIdx.y, qt = blockIdx.x;
  int lane = threadIdx.x;
  size_t o1 = (size_t)bh * T_SEQ * HD;
  const u16* Qh = qhp + o1; const u16* Ql = qlp + o1;
  const u16* Kh = khp + o1; const u16* Kl = klp + o1;
  const u16* Vh = vth + o1; const u16* Vl = vtl + o1;
  int q0 = qt * 32;
  int l15 = lane & 15, lg = lane >> 4, kof = lg * 8;
  bf16x8 aqh[2][2], aql[2][2];
  for (int m = 0; m < 2; ++m)
    for (int kc = 0; kc < 2; ++kc) {
      size_t p = (size_t)(q0 + 16 * m + l15) * HD + kc * 32 + kof;
      aqh[m][kc] = ld8(Qh + p);
      aql[m][kc] = ld8(Ql + p);
    }
  f32x4 o[2][4] = {};
  float mrow[2][4], lrow[2][4];
  for (int m = 0; m < 2; ++m)
    for (int r = 0; r < 4; ++r) { mrow[m][r] = -1e30f; lrow[m][r] = 0.f; }
  __shared__ __align__(16) float P_s[32][36];
  for (int j = 0; j <= qt; ++j) {
    int t0 = j * 32;
    bf16x8 bkh[2][2], bkl[2][2];
    for (int n = 0; n < 2; ++n)
      for (int kc = 0; kc < 2; ++kc) {
        size_t p = (size_t)(t0 + 16 * n + l15) * HD + kc * 32 + kof;
        bkh[n][kc] = ld8(Kh + p);
        bkl[n][kc] = ld8(Kl + p);
      }
    f32x4 sfr[2][2];
    for (int m = 0; m < 2; ++m)
      for (int n = 0; n < 2; ++n) {
        f32x4 z = {};
        for (int kc = 0; kc < 2; ++kc) {
          z = MFMA16(aql[m][kc], bkh[n][kc], z);
          z = MFMA16(aqh[m][kc], bkl[n][kc], z);
          z = MFMA16(aqh[m][kc], bkh[n][kc], z);
        }
        sfr[m][n] = z;
      }
    for (int m = 0; m < 2; ++m) {
      for (int r = 0; r < 4; ++r) {
        int grow = q0 + 16 * m + lg * 4 + r;
        float v0 = sfr[m][0][r] * 0.125f;
        float v1 = sfr[m][1][r] * 0.125f;
        if (t0 + l15 > grow) v0 = -1e30f;
        if (t0 + 16 + l15 > grow) v1 = -1e30f;
        float mx = fmaxf(v0, v1);
        for (int off = 8; off >= 1; off >>= 1) mx = fmaxf(mx, __shfl_xor(mx, off));
        float mnew = fmaxf(mrow[m][r], mx);
        float alpha = __expf(mrow[m][r] - mnew);
        float p0 = __expf(v0 - mnew);
        float p1 = __expf(v1 - mnew);
        float ps = p0 + p1;
        for (int off = 8; off >= 1; off >>= 1) ps += __shfl_xor(ps, off);
        mrow[m][r] = mnew;
        lrow[m][r] = lrow[m][r] * alpha + ps;
        for (int dt = 0; dt < 4; ++dt) o[m][dt][r] *= alpha;
        P_s[16 * m + lg * 4 + r][l15] = p0;
        P_s[16 * m + lg * 4 + r][l15 + 16] = p1;
      }
    }
    __syncthreads();
    bf16x8 ph[2], pl[2];
    for (int m = 0; m < 2; ++m)
      for (int jj = 0; jj < 8; ++jj) {
        float vv = P_s[16 * m + l15][kof + jj];
        u16 hv = f2bf(vv);
        ph[m][jj] = __builtin_bit_cast(__bf16, hv);
        pl[m][jj] = __builtin_bit_cast(__bf16, f2bf(vv - bf2f(hv)));
      }
    __syncthreads();
    for (int m = 0; m < 2; ++m)
      for (int dt = 0; dt < 4; ++dt) {
        size_t vp = (size_t)(dt * 16 + l15) * T_SEQ + t0 + kof;
        bf16x8 bvh = ld8(Vh + vp);
        bf16x8 bvl = ld8(Vl + vp);
        o[m][dt] = MFMA16(pl[m], bvh, o[m][dt]);
        o[m][dt] = MFMA16(ph[m], bvl, o[m][dt]);
        o[m][dt] = MFMA16(ph[m], bvh, o[m][dt]);
      }
  }
  int b = bh >> 4, h = bh & 15;
  for (int m = 0; m < 2; ++m)
    for (int r = 0; r < 4; ++r) {
      float inv = 1.f / lrow[m][r];
      int grow = q0 + 16 * m + lg * 4 + r;
      for (int dt = 0; dt < 4; ++dt)
        y[((size_t)b * T_SEQ + grow) * CDIM + h * HD + dt * 16 + l15] = o[m][dt][r] * inv;
    }
}

// ---- MoE GEMM: A bf16, B fp32 (cast inline).
// MODE 0: fc (gather+relu^2 -> bf16 hid); MODE 1: proj (scatter + residual -> FP32 out)
template <int MODE>
__global__ __launch_bounds__(256) void gemm_moe_k(const u16* __restrict__ Abf, const float* __restrict__ Ball,
                                                  void* __restrict__ Cout, const float* __restrict__ Xadd,
                                                  const int* __restrict__ perm, const int* __restrict__ cnt,
                                                  const int* __restrict__ offs) {
  const int N = (MODE == 0) ? 4096 : 1024;
  const int K = (MODE == 0) ? 1024 : 4096;
  int e = blockIdx.z;
  int Me = cnt[e];
  int m0 = blockIdx.y * 128;
  if (m0 >= Me) return;
  int n0 = blockIdx.x * 128;
  int offE = offs[e];
  const int* permE = perm + offE;
  const float* B = Ball + (size_t)e * (size_t)K * (size_t)N;
  __shared__ __align__(16) u16 As[128][LDKs];
  __shared__ __align__(16) u16 Bs[128][LDKs];
  int tid = threadIdx.x, lane = tid & 63, w = tid >> 6;
  int wr = w >> 1, wc = w & 1;
  int fr = lane & 15, fq = lane >> 4, kof = fq * 8;
  f32x4 acc[4][4] = {};
  for (int kt = 0; kt < K; kt += 64) {
    #pragma unroll
    for (int i = 0; i < 4; ++i) {
      int slot = tid + i * 256;
      int r = slot >> 3, col = (slot & 7) * 8;
      const u16* src;
      if (MODE == 0) {
        int gr = m0 + r;
        int tok = permE[gr < Me ? gr : 0];
        src = Abf + (size_t)tok * K + kt + col;
      } else {
        int gr = m0 + r; if (gr >= Me) gr = Me - 1;
        src = Abf + (size_t)(offE + gr) * K + kt + col;
      }
      *(uint4*)&As[r][col] = *(const uint4*)src;
    }
    #pragma unroll
    for (int i = 0; i < 2; ++i) {
      int sub = tid + i * 256;
      int nb = (sub & 31) * 4;
      int kk0 = (sub >> 5) * 4;
      float4 r0 = *(const float4*)(B + (size_t)(kt + kk0 + 0) * N + n0 + nb);
      float4 r1 = *(const float4*)(B + (size_t)(kt + kk0 + 1) * N + n0 + nb);
      float4 r2 = *(const float4*)(B + (size_t)(kt + kk0 + 2) * N + n0 + nb);
      float4 r3 = *(const float4*)(B + (size_t)(kt + kk0 + 3) * N + n0 + nb);
      float cv[4][4] = {{r0.x, r1.x, r2.x, r3.x}, {r0.y, r1.y, r2.y, r3.y},
                        {r0.z, r1.z, r2.z, r3.z}, {r0.w, r1.w, r2.w, r3.w}};
      #pragma unroll
      for (int c = 0; c < 4; ++c) {
        int n = nb + c;
        int kp = BSWZ(n, kk0);
        ushort4 hi;
        hi.x = f2bf(cv[c][0]); hi.y = f2bf(cv[c][1]);
        hi.z = f2bf(cv[c][2]); hi.w = f2bf(cv[c][3]);
        *(ushort4*)&Bs[n][kp] = hi;
      }
    }
    __syncthreads();
    #pragma unroll
    for (int ks = 0; ks < 2; ++ks) {
      int kk = ks * 32 + kof;
      bf16x8 af[4], bfr[4];
      #pragma unroll
      for (int i = 0; i < 4; ++i) af[i] = ld8(&As[wr * 64 + i * 16 + fr][kk]);
      #pragma unroll
      for (int j = 0; j < 4; ++j) {
        int n = wc * 64 + j * 16 + fr;
        bfr[j] = ld8(&Bs[n][BSWZ(n, kk)]);
      }
      #pragma unroll
      for (int i = 0; i < 4; ++i)
        #pragma unroll
        for (int j = 0; j < 4; ++j)
          acc[i][j] = MFMA16(af[i], bfr[j], acc[i][j]);
    }
    __syncthreads();
  }
  #pragma unroll
  for (int i = 0; i < 4; ++i)
    #pragma unroll
    for (int j = 0; j < 4; ++j) {
      int lrow = wr * 64 + i * 16 + fq * 4 + j;
      int gm = m0 + lrow;
      if (gm >= Me) continue;
      #pragma unroll
      for (int jf = 0; jf < 4; ++jf) {
        int gn = n0 + wc * 64 + jf * 16 + fr;
        float v = acc[i][jf][j];
        if (MODE == 0) {
          float rv = fmaxf(v, 0.f);
          ((u16*)Cout)[(size_t)(offE + gm) * N + gn] = f2bf(rv * rv);
        } else {
          int tok = permE[gm];
          ((float*)Cout)[(size_t)tok * N + gn] = Xadd[(size_t)tok * N + gn] + v;
        }
      }
    }
}

// ---- router: inline rms + fp32 logits + per-token stats
__global__ __launch_bounds__(64) void router_k(const float* __restrict__ xnew, const float* __restrict__ Wr,
                                               int* __restrict__ eidx, int* __restrict__ cnt,
                                               float* __restrict__ ts) {
  int t = blockIdx.x, lane = threadIdx.x;
  const float* h = xnew + (size_t)t * CDIM;
  float a0 = 0, a1 = 0, a2 = 0, a3 = 0, ss = 0;
  for (int i = lane; i < CDIM; i += 64) {
    float hv = h[i];
    ss += hv * hv;
    float4 wr = ((const float4*)Wr)[i];
    a0 += hv * wr.x; a1 += hv * wr.y; a2 += hv * wr.z; a3 += hv * wr.w;
  }
  for (int off = 32; off >= 1; off >>= 1) {
    a0 += __shfl_xor(a0, off); a1 += __shfl_xor(a1, off);
    a2 += __shfl_xor(a2, off); a3 += __shfl_xor(a3, off);
    ss += __shfl_xor(ss, off);
  }
  if (lane == 0) {
    float rs = 1.0f / sqrtf(ss * (1.f / CDIM) + EPS_RMS);
    float l[4] = {a0 * rs, a1 * rs, a2 * rs, a3 * rs};
    int am = 0; float mx = l[0];
    for (int e = 1; e < 4; ++e) if (l[e] > mx) { mx = l[e]; am = e; }
    float p[4], sum = 0;
    for (int e = 0; e < 4; ++e) { p[e] = __expf(l[e] - mx); sum += p[e]; }
    float lse = mx + logf(sum);
    float H = 0;
    for (int e = 0; e < 4; ++e) {
      float pr = p[e] / sum;
      H -= pr * logf(pr + 1e-9f);
      ts[t * 8 + e] = pr;
    }
    ts[t * 8 + 4] = H;
    ts[t * 8 + 5] = lse * lse;
    atomicAdd(&cnt[am], 1);
    eidx[t] = am;
  }
}

// ---- deterministic stats reduce + finalize (FP32 out)
__global__ __launch_bounds__(256) void reduce_k(const float* __restrict__ ts, const int* __restrict__ cnt,
                                                int* __restrict__ offs, int* __restrict__ cursor,
                                                float* __restrict__ outs) {
  __shared__ float buf[6][256];
  int tid = threadIdx.x;
  float s[6] = {0, 0, 0, 0, 0, 0};
  for (int t = tid; t < NTOK; t += 256)
    for (int k = 0; k < 6; ++k) s[k] += ts[t * 8 + k];
  for (int k = 0; k < 6; ++k) buf[k][tid] = s[k];
  __syncthreads();
  for (int st = 128; st >= 1; st >>= 1) {
    if (tid < st)
      for (int k = 0; k < 6; ++k) buf[k][tid] += buf[k][tid + st];
    __syncthreads();
  }
  if (tid == 0) {
    int o = 0;
    for (int e = 0; e < 4; ++e) { offs[e] = o; o += cnt[e]; cursor[e] = 0; }
    float aux = 0;
    for (int e = 0; e < 4; ++e)
      aux += ((float)cnt[e] * (1.f / NTOK)) * (buf[e][0] * (1.f / NTOK));
    outs[0] = 4.f * aux;
    outs[1] = buf[5][0] * (1.f / NTOK);
    outs[2] = (buf[4][0] * (1.f / NTOK)) / logf(4.f);
    for (int e = 0; e < 4; ++e) outs[3 + e] = (float)cnt[e] * (1.f / NTOK);
  }
}

__global__ __launch_bounds__(256) void scatter_k(const int* __restrict__ eidx, const int* __restrict__ offs,
                                                 int* __restrict__ cursor, int* __restrict__ perm) {
  int t = blockIdx.x * 256 + threadIdx.x;
  if (t >= NTOK) return;
  int e = eidx[t];
  int pos = atomicAdd(&cursor[e], 1);
  perm[offs[e] + pos] = t;
}

extern "C" void kernel_launch(void* const* d_in, const int* in_sizes, int n_in,
                              void* d_out, int out_size, void* d_ws, size_t ws_size,
                              hipStream_t stream) {
  (void)in_sizes; (void)n_in; (void)out_size; (void)ws_size;
  const float* x   = (const float*)d_in[0];
  const float* Wq  = (const float*)d_in[1];
  const float* Wk  = (const float*)d_in[2];
  const float* Wv  = (const float*)d_in[3];
  const float* Wo  = (const float*)d_in[4];
  const float* Wr  = (const float*)d_in[5];
  const float* Wfc = (const float*)d_in[6];
  const float* Wpr = (const float*)d_in[7];
  float* out = (float*)d_out;                   // reference output dtype = FLOAT32
  uint8_t* ws = (uint8_t*)d_ws;

  size_t off = 0;
  auto alloc = [&](size_t b) { size_t p = off; off += (b + 255) & ~(size_t)255; return p; };
  float* ropeC = (float*)(ws + alloc(262144));
  float* ropeS = (float*)(ws + alloc(262144));
  float* ts    = (float*)(ws + alloc(131072));
  int* eidx = (int*)(ws + alloc(16384));
  int* perm = (int*)(ws + alloc(16384));
  uint8_t* stats = ws + alloc(256);
  int* cnt = (int*)stats;
  int* offsv = cnt + 4;
  int* cursor = cnt + 8;
  float* h1  = (float*)(ws + alloc(16777216));  // -> xnew after attn
  u16* qh = (u16*)(ws + alloc(8388608));
  u16* ql = (u16*)(ws + alloc(8388608));
  u16* kh = (u16*)(ws + alloc(8388608));        // -> h2b after attn
  u16* kl = (u16*)(ws + alloc(8388608));
  u16* vh = (u16*)(ws + alloc(8388608));        // -> yb (with vl) -> hid base
  u16* vl = (u16*)(ws + alloc(8388608));
  u16* vth = (u16*)(ws + alloc(8388608));
  u16* vtl = (u16*)(ws + alloc(8388608));
  // lifetime-disjoint aliases:
  float* xnew = h1;         // h1 dead after V-GEMM; written by Wo-GEMM
  float* yb   = (float*)vh; // vh/vl dead after vtrans; written by attn
  u16* h2b    = kh;         // kh dead after attn
  u16* hid    = vh;         // spans vh+vl+vth+vtl = 33.55MB, dead after attn/Wo

  hipMemsetAsync(stats, 0, 256, stream);
  rope_table_k<<<256, 256, 0, stream>>>(ropeC, ropeS);
  rmsnorm_f_k<<<NTOK, 256, 0, stream>>>(x, h1);

  gemm_split_k<0><<<dim3(8, 32), 256, 0, stream>>>(h1, Wq, nullptr, nullptr, qh, ql, ropeC, ropeS);
  gemm_split_k<0><<<dim3(8, 32), 256, 0, stream>>>(h1, Wk, nullptr, nullptr, kh, kl, ropeC, ropeS);
  gemm_split_k<1><<<dim3(8, 32), 256, 0, stream>>>(h1, Wv, nullptr, nullptr, vh, vl, nullptr, nullptr);
  vtrans_k<<<dim3(32, 32, 2), 256, 0, stream>>>(vh, vl, vth, vtl);
  attn_k<<<dim3(64, 32), 64, 0, stream>>>(qh, ql, kh, kl, vth, vtl, yb);
  gemm_split_k<2><<<dim3(8, 32), 256, 0, stream>>>(yb, Wo, x, xnew, nullptr, nullptr, nullptr, nullptr);

  rmsnorm_b_k<<<NTOK, 256, 0, stream>>>(xnew, h2b);
  router_k<<<NTOK, 64, 0, stream>>>(xnew, Wr, eidx, cnt, ts);
  reduce_k<<<1, 256, 0, stream>>>(ts, cnt, offsv, cursor, out + 4194304);
  scatter_k<<<16, 256, 0, stream>>>(eidx, offsv, cursor, perm);
  gemm_moe_k<0><<<dim3(32, 32, 4), 256, 0, stream>>>(h2b, Wfc, hid, nullptr, perm, cnt, offsv);
  gemm_moe_k<1><<<dim3(8, 32, 4), 256, 0, stream>>>(hid, Wpr, out, xnew, perm, cnt, offsv);
}

// Round 6
// 1020.001 us; speedup vs baseline: 1.0407x; 1.0407x over previous
//
#include <hip/hip_runtime.h>
#include <stdint.h>

typedef unsigned short u16;
typedef __attribute__((ext_vector_type(8))) __bf16 bf16x8;
typedef __attribute__((ext_vector_type(4))) float f32x4;

#define T_SEQ 2048
#define CDIM 1024
#define NH 16
#define HD 64
#define NTOK 4096
#define EPS_RMS 1.1920929e-07f
#define LDKs 72

__device__ __forceinline__ u16 f2bf(float x) {
  union { float f; uint32_t u; } v; v.f = x;
  uint32_t r = v.u + 0x7fffu + ((v.u >> 16) & 1u);
  return (u16)(r >> 16);
}
__device__ __forceinline__ float bf2f(u16 h) {
  union { uint32_t u; float f; } v; v.u = ((uint32_t)h) << 16; return v.f;
}
__device__ __forceinline__ bf16x8 ld8(const u16* p) {
  uint4 q = *(const uint4*)p;
  return __builtin_bit_cast(bf16x8, q);
}
#define MFMA16(a, b, c) __builtin_amdgcn_mfma_f32_16x16x32_bf16((a), (b), (c), 0, 0, 0)

// ---- rope table
__global__ __launch_bounds__(256) void rope_table_k(float* __restrict__ cosT, float* __restrict__ sinT) {
  int idx = blockIdx.x * 256 + threadIdx.x;   // T*32
  int t = idx >> 5, d = idx & 31;
  float inv = 1.0f / powf(10000.0f, (float)(2 * d) / 64.0f);
  float a = (float)t * inv;
  cosT[idx] = cosf(a);
  sinT[idx] = sinf(a);
}

// ---- transpose + SPLIT fp32 (R x Cc) -> bf16 hi + lo (Cc x R)
__global__ __launch_bounds__(256) void wsplit_k(const float* __restrict__ in,
                                                u16* __restrict__ ohi, u16* __restrict__ olo,
                                                int R, int Cc) {
  __shared__ float tile[32][33];
  int c0 = blockIdx.x * 32, r0 = blockIdx.y * 32;
  int tx = threadIdx.x & 31, ty = threadIdx.x >> 5;
  for (int i = ty; i < 32; i += 8)
    tile[i][tx] = in[(size_t)(r0 + i) * Cc + (c0 + tx)];
  __syncthreads();
  for (int i = ty; i < 32; i += 8) {
    float v = tile[tx][i];
    u16 h = f2bf(v);
    ohi[(size_t)(c0 + i) * R + (r0 + tx)] = h;
    olo[(size_t)(c0 + i) * R + (r0 + tx)] = f2bf(v - bf2f(h));
  }
}

// ---- transpose + cast fp32 (R x Cc) -> bf16 (Cc x R), z-batched
__global__ __launch_bounds__(256) void wcast_k(const float* __restrict__ in,
                                               u16* __restrict__ out, int R, int Cc) {
  size_t zoff = (size_t)blockIdx.z * (size_t)R * (size_t)Cc;
  in += zoff; out += zoff;
  __shared__ float tile[32][33];
  int c0 = blockIdx.x * 32, r0 = blockIdx.y * 32;
  int tx = threadIdx.x & 31, ty = threadIdx.x >> 5;
  for (int i = ty; i < 32; i += 8)
    tile[i][tx] = in[(size_t)(r0 + i) * Cc + (c0 + tx)];
  __syncthreads();
  for (int i = ty; i < 32; i += 8)
    out[(size_t)(c0 + i) * R + (r0 + tx)] = f2bf(tile[tx][i]);
}

// ---- rmsnorm over C=1024, split hi/lo bf16 out
__global__ __launch_bounds__(256) void rmsnorm_split_k(const float* __restrict__ x,
                                                       u16* __restrict__ hh, u16* __restrict__ hl) {
  int row = blockIdx.x;
  const float* xr = x + (size_t)row * CDIM;
  int tid = threadIdx.x;
  float v[4]; float s = 0.f;
  for (int i = 0; i < 4; ++i) { v[i] = xr[tid + 256 * i]; s += v[i] * v[i]; }
  for (int off = 32; off >= 1; off >>= 1) s += __shfl_xor(s, off);
  __shared__ float red[4];
  int w = tid >> 6, lane = tid & 63;
  if (lane == 0) red[w] = s;
  __syncthreads();
  s = red[0] + red[1] + red[2] + red[3];
  float rs = 1.0f / sqrtf(s * (1.f / CDIM) + EPS_RMS);
  for (int i = 0; i < 4; ++i) {
    float o = v[i] * rs;
    u16 h = f2bf(o);
    hh[(size_t)row * CDIM + tid + 256 * i] = h;
    hl[(size_t)row * CDIM + tid + 256 * i] = f2bf(o - bf2f(h));
  }
}

// ---- rmsnorm bf16 out
__global__ __launch_bounds__(256) void rmsnorm_b_k(const float* __restrict__ x, u16* __restrict__ hb) {
  int row = blockIdx.x;
  const float* xr = x + (size_t)row * CDIM;
  int tid = threadIdx.x;
  float v[4]; float s = 0.f;
  for (int i = 0; i < 4; ++i) { v[i] = xr[tid + 256 * i]; s += v[i] * v[i]; }
  for (int off = 32; off >= 1; off >>= 1) s += __shfl_xor(s, off);
  __shared__ float red[4];
  int w = tid >> 6, lane = tid & 63;
  if (lane == 0) red[w] = s;
  __syncthreads();
  s = red[0] + red[1] + red[2] + red[3];
  float rs = 1.0f / sqrtf(s * (1.f / CDIM) + EPS_RMS);
  for (int i = 0; i < 4; ++i) hb[(size_t)row * CDIM + tid + 256 * i] = f2bf(v[i] * rs);
}

// ---- split GEMM, all operands PRE-SPLIT bf16: C = A(M x K) * B^T (N x K)
// 3-product Ootomo accumulate. EPI 0: per-head RMS+rope -> (b,h,t,d) hi/lo.
// EPI 1: split store (b,t,c). EPI 2: fp32 out = Xadd + acc.
template <int EPI>
__global__ __launch_bounds__(256) void gemm_sp_k(const u16* __restrict__ Ahp, const u16* __restrict__ Alp,
                                                 const u16* __restrict__ Bhp, const u16* __restrict__ Blp,
                                                 const float* __restrict__ Xadd, float* __restrict__ outF,
                                                 u16* __restrict__ outH, u16* __restrict__ outL,
                                                 const float* __restrict__ cosT, const float* __restrict__ sinT) {
  const int N = CDIM, K = CDIM;
  __shared__ __align__(16) u16 Ah[128][LDKs];
  __shared__ __align__(16) u16 Al[128][LDKs];
  __shared__ __align__(16) u16 Bh[128][LDKs];
  __shared__ __align__(16) u16 Bl[128][LDKs];
  int m0 = blockIdx.y * 128, n0 = blockIdx.x * 128;
  int tid = threadIdx.x, lane = tid & 63, w = tid >> 6;
  int wr = w >> 1, wc = w & 1;
  int fr = lane & 15, fq = lane >> 4, kof = fq * 8;
  int rB = tid >> 3, colB = (tid & 7) * 8;
  f32x4 acc[4][4] = {};
  for (int kt = 0; kt < K; kt += 64) {
    #pragma unroll
    for (int i = 0; i < 4; ++i) {
      int r = rB + i * 32;
      *(uint4*)&Ah[r][colB] = *(const uint4*)(Ahp + (size_t)(m0 + r) * K + kt + colB);
      *(uint4*)&Al[r][colB] = *(const uint4*)(Alp + (size_t)(m0 + r) * K + kt + colB);
      *(uint4*)&Bh[r][colB] = *(const uint4*)(Bhp + (size_t)(n0 + r) * K + kt + colB);
      *(uint4*)&Bl[r][colB] = *(const uint4*)(Blp + (size_t)(n0 + r) * K + kt + colB);
    }
    __syncthreads();
    #pragma unroll
    for (int ks = 0; ks < 2; ++ks) {
      int kk = ks * 32 + kof;
      bf16x8 ah[4], al[4], bh4[4], bl4[4];
      #pragma unroll
      for (int i = 0; i < 4; ++i) {
        ah[i] = ld8(&Ah[wr * 64 + i * 16 + fr][kk]);
        al[i] = ld8(&Al[wr * 64 + i * 16 + fr][kk]);
      }
      #pragma unroll
      for (int j = 0; j < 4; ++j) {
        bh4[j] = ld8(&Bh[wc * 64 + j * 16 + fr][kk]);
        bl4[j] = ld8(&Bl[wc * 64 + j * 16 + fr][kk]);
      }
      #pragma unroll
      for (int i = 0; i < 4; ++i)
        #pragma unroll
        for (int j = 0; j < 4; ++j) {
          acc[i][j] = MFMA16(al[i], bh4[j], acc[i][j]);
          acc[i][j] = MFMA16(ah[i], bl4[j], acc[i][j]);
          acc[i][j] = MFMA16(ah[i], bh4[j], acc[i][j]);
        }
    }
    __syncthreads();
  }
  if (EPI == 0) {
    int h = (n0 + wc * 64) >> 6;
    #pragma unroll
    for (int i = 0; i < 4; ++i) {
      #pragma unroll
      for (int j = 0; j < 4; ++j) {
        int row = m0 + wr * 64 + i * 16 + fq * 4 + j;
        float v0 = acc[i][0][j], v1 = acc[i][1][j], v2 = acc[i][2][j], v3 = acc[i][3][j];
        float ss = v0 * v0 + v1 * v1 + v2 * v2 + v3 * v3;
        ss += __shfl_xor(ss, 1); ss += __shfl_xor(ss, 2);
        ss += __shfl_xor(ss, 4); ss += __shfl_xor(ss, 8);
        float rs = 1.0f / sqrtf(ss * (1.f / HD) + EPS_RMS);
        float x0 = v0 * rs, x1 = v1 * rs, x2 = v2 * rs, x3 = v3 * rs;
        int t = row & (T_SEQ - 1), b = row >> 11;
        float c0 = cosT[t * 32 + fr],      s0 = sinT[t * 32 + fr];
        float c1 = cosT[t * 32 + fr + 16], s1 = sinT[t * 32 + fr + 16];
        float o0 = x0 * c0 + x2 * s0;
        float o1 = x1 * c1 + x3 * s1;
        float o2 = x2 * c0 - x0 * s0;
        float o3 = x3 * c1 - x1 * s1;
        size_t base = ((size_t)(b * NH + h) * T_SEQ + t) * HD + fr;
        u16 hh;
        hh = f2bf(o0); outH[base]      = hh; outL[base]      = f2bf(o0 - bf2f(hh));
        hh = f2bf(o1); outH[base + 16] = hh; outL[base + 16] = f2bf(o1 - bf2f(hh));
        hh = f2bf(o2); outH[base + 32] = hh; outL[base + 32] = f2bf(o2 - bf2f(hh));
        hh = f2bf(o3); outH[base + 48] = hh; outL[base + 48] = f2bf(o3 - bf2f(hh));
      }
    }
  } else {
    #pragma unroll
    for (int i = 0; i < 4; ++i)
      #pragma unroll
      for (int j = 0; j < 4; ++j) {
        int row = m0 + wr * 64 + i * 16 + fq * 4 + j;
        #pragma unroll
        for (int jf = 0; jf < 4; ++jf) {
          int gn = n0 + wc * 64 + jf * 16 + fr;
          float v = acc[i][jf][j];
          if (EPI == 1) {
            u16 hh = f2bf(v);
            outH[(size_t)row * CDIM + gn] = hh;
            outL[(size_t)row * CDIM + gn] = f2bf(v - bf2f(hh));
          } else {
            outF[(size_t)row * CDIM + gn] = Xadd[(size_t)row * CDIM + gn] + v;
          }
        }
      }
  }
}

// ---- transpose v (bf16): (b,t,h,d) -> (b,h,d,t); z selects hi/lo
__global__ __launch_bounds__(256) void vtrans_k(const u16* __restrict__ vhp, const u16* __restrict__ vlp,
                                                u16* __restrict__ vthp, u16* __restrict__ vtlp) {
  const u16* src = blockIdx.z ? vlp : vhp;
  u16* dst = blockIdx.z ? vtlp : vthp;
  __shared__ u16 t_[64][65];
  int bh = blockIdx.y, b = bh >> 4, h = bh & 15;
  int t0 = blockIdx.x * 64;
  const u16* in = src + ((size_t)b * T_SEQ) * CDIM + (size_t)h * HD;
  u16* out = dst + (size_t)bh * HD * T_SEQ;
  int tx = threadIdx.x & 63, ty = threadIdx.x >> 6;
  for (int i = ty; i < 64; i += 4) t_[i][tx] = in[(size_t)(t0 + i) * CDIM + tx];
  __syncthreads();
  for (int i = ty; i < 64; i += 4) out[(size_t)i * T_SEQ + t0 + tx] = t_[tx][i];
}

// ---- flash attention (split precision), 1 wave / 32 q-rows, KV blocks of 32
// writes y SPLIT (hi/lo bf16) for the Wo split-GEMM
__global__ __launch_bounds__(64) void attn_k(const u16* __restrict__ qhp, const u16* __restrict__ qlp,
                                             const u16* __restrict__ khp, const u16* __restrict__ klp,
                                             const u16* __restrict__ vth, const u16* __restrict__ vtl,
                                             u16* __restrict__ yh, u16* __restrict__ yl) {
  int bh = blockIdx.y, qt = blockIdx.x;
  int lane = threadIdx.x;
  size_t o1 = (size_t)bh * T_SEQ * HD;
  const u16* Qh = qhp + o1; const u16* Ql = qlp + o1;
  const u16* Kh = khp + o1; const u16* Kl = klp + o1;
  const u16* Vh = vth + o1; const u16* Vl = vtl + o1;
  int q0 = qt * 32;
  int l15 = lane & 15, lg = lane >> 4, kof = lg * 8;
  bf16x8 aqh[2][2], aql[2][2];
  for (int m = 0; m < 2; ++m)
    for (int kc = 0; kc < 2; ++kc) {
      size_t p = (size_t)(q0 + 16 * m + l15) * HD + kc * 32 + kof;
      aqh[m][kc] = ld8(Qh + p);
      aql[m][kc] = ld8(Ql + p);
    }
  f32x4 o[2][4] = {};
  float mrow[2][4], lrow[2][4];
  for (int m = 0; m < 2; ++m)
    for (int r = 0; r < 4; ++r) { mrow[m][r] = -1e30f; lrow[m][r] = 0.f; }
  __shared__ __align__(16) float P_s[32][36];
  for (int j = 0; j <= qt; ++j) {
    int t0 = j * 32;
    bf16x8 bkh[2][2], bkl[2][2];
    for (int n = 0; n < 2; ++n)
      for (int kc = 0; kc < 2; ++kc) {
        size_t p = (size_t)(t0 + 16 * n + l15) * HD + kc * 32 + kof;
        bkh[n][kc] = ld8(Kh + p);
        bkl[n][kc] = ld8(Kl + p);
      }
    f32x4 sfr[2][2];
    for (int m = 0; m < 2; ++m)
      for (int n = 0; n < 2; ++n) {
        f32x4 z = {};
        for (int kc = 0; kc < 2; ++kc) {
          z = MFMA16(aql[m][kc], bkh[n][kc], z);
          z = MFMA16(aqh[m][kc], bkl[n][kc], z);
          z = MFMA16(aqh[m][kc], bkh[n][kc], z);
        }
        sfr[m][n] = z;
      }
    for (int m = 0; m < 2; ++m) {
      for (int r = 0; r < 4; ++r) {
        int grow = q0 + 16 * m + lg * 4 + r;
        float v0 = sfr[m][0][r] * 0.125f;
        float v1 = sfr[m][1][r] * 0.125f;
        if (t0 + l15 > grow) v0 = -1e30f;
        if (t0 + 16 + l15 > grow) v1 = -1e30f;
        float mx = fmaxf(v0, v1);
        for (int off = 8; off >= 1; off >>= 1) mx = fmaxf(mx, __shfl_xor(mx, off));
        float mnew = fmaxf(mrow[m][r], mx);
        float alpha = __expf(mrow[m][r] - mnew);
        float p0 = __expf(v0 - mnew);
        float p1 = __expf(v1 - mnew);
        float ps = p0 + p1;
        for (int off = 8; off >= 1; off >>= 1) ps += __shfl_xor(ps, off);
        mrow[m][r] = mnew;
        lrow[m][r] = lrow[m][r] * alpha + ps;
        for (int dt = 0; dt < 4; ++dt) o[m][dt][r] *= alpha;
        P_s[16 * m + lg * 4 + r][l15] = p0;
        P_s[16 * m + lg * 4 + r][l15 + 16] = p1;
      }
    }
    __syncthreads();
    bf16x8 ph[2], pl[2];
    for (int m = 0; m < 2; ++m)
      for (int jj = 0; jj < 8; ++jj) {
        float vv = P_s[16 * m + l15][kof + jj];
        u16 hv = f2bf(vv);
        ph[m][jj] = __builtin_bit_cast(__bf16, hv);
        pl[m][jj] = __builtin_bit_cast(__bf16, f2bf(vv - bf2f(hv)));
      }
    __syncthreads();
    for (int m = 0; m < 2; ++m)
      for (int dt = 0; dt < 4; ++dt) {
        size_t vp = (size_t)(dt * 16 + l15) * T_SEQ + t0 + kof;
        bf16x8 bvh = ld8(Vh + vp);
        bf16x8 bvl = ld8(Vl + vp);
        o[m][dt] = MFMA16(pl[m], bvh, o[m][dt]);
        o[m][dt] = MFMA16(ph[m], bvl, o[m][dt]);
        o[m][dt] = MFMA16(ph[m], bvh, o[m][dt]);
      }
  }
  int b = bh >> 4, h = bh & 15;
  for (int m = 0; m < 2; ++m)
    for (int r = 0; r < 4; ++r) {
      float inv = 1.f / lrow[m][r];
      int grow = q0 + 16 * m + lg * 4 + r;
      for (int dt = 0; dt < 4; ++dt) {
        size_t idx = ((size_t)b * T_SEQ + grow) * CDIM + h * HD + dt * 16 + l15;
        float vv = o[m][dt][r] * inv;
        u16 hh = f2bf(vv);
        yh[idx] = hh;
        yl[idx] = f2bf(vv - bf2f(hh));
      }
    }
}

// ---- MoE GEMM: A bf16, B bf16 pre-cast (NxK k-contig per expert).
// MODE 0: fc (gather rows via perm, relu^2 -> bf16 hid). MODE 1: proj (scatter + residual -> fp32 out)
template <int MODE>
__global__ __launch_bounds__(256) void gemm_moe_k(const u16* __restrict__ Abf, const u16* __restrict__ BT,
                                                  void* __restrict__ Cout, const float* __restrict__ Xadd,
                                                  const int* __restrict__ perm, const int* __restrict__ cnt,
                                                  const int* __restrict__ offs) {
  const int N = (MODE == 0) ? 4096 : 1024;
  const int K = (MODE == 0) ? 1024 : 4096;
  int e = blockIdx.z;
  int Me = cnt[e];
  int m0 = blockIdx.y * 128;
  if (m0 >= Me) return;
  int n0 = blockIdx.x * 128;
  int offE = offs[e];
  const int* permE = perm + offE;
  const u16* BTe = BT + (size_t)e * (size_t)N * (size_t)K;
  __shared__ __align__(16) u16 As[128][LDKs];
  __shared__ __align__(16) u16 Bs[128][LDKs];
  int tid = threadIdx.x, lane = tid & 63, w = tid >> 6;
  int wr = w >> 1, wc = w & 1;
  int fr = lane & 15, fq = lane >> 4, kof = fq * 8;
  int rB = tid >> 3, colB = (tid & 7) * 8;
  // hoist gathered row base pointers out of the k-loop
  const u16* asrc[4];
  #pragma unroll
  for (int i = 0; i < 4; ++i) {
    int gr = m0 + rB + i * 32;
    if (MODE == 0) {
      int tok = permE[gr < Me ? gr : 0];
      asrc[i] = Abf + (size_t)tok * K;
    } else {
      if (gr >= Me) gr = Me - 1;
      asrc[i] = Abf + (size_t)(offE + gr) * K;
    }
  }
  f32x4 acc[4][4] = {};
  for (int kt = 0; kt < K; kt += 64) {
    #pragma unroll
    for (int i = 0; i < 4; ++i) {
      int r = rB + i * 32;
      *(uint4*)&As[r][colB] = *(const uint4*)(asrc[i] + kt + colB);
      *(uint4*)&Bs[r][colB] = *(const uint4*)(BTe + (size_t)(n0 + r) * K + kt + colB);
    }
    __syncthreads();
    #pragma unroll
    for (int ks = 0; ks < 2; ++ks) {
      int kk = ks * 32 + kof;
      bf16x8 af[4], bfr[4];
      #pragma unroll
      for (int i = 0; i < 4; ++i) af[i] = ld8(&As[wr * 64 + i * 16 + fr][kk]);
      #pragma unroll
      for (int j = 0; j < 4; ++j) bfr[j] = ld8(&Bs[wc * 64 + j * 16 + fr][kk]);
      #pragma unroll
      for (int i = 0; i < 4; ++i)
        #pragma unroll
        for (int j = 0; j < 4; ++j)
          acc[i][j] = MFMA16(af[i], bfr[j], acc[i][j]);
    }
    __syncthreads();
  }
  #pragma unroll
  for (int i = 0; i < 4; ++i)
    #pragma unroll
    for (int j = 0; j < 4; ++j) {
      int lrow = wr * 64 + i * 16 + fq * 4 + j;
      int gm = m0 + lrow;
      if (gm >= Me) continue;
      #pragma unroll
      for (int jf = 0; jf < 4; ++jf) {
        int gn = n0 + wc * 64 + jf * 16 + fr;
        float v = acc[i][jf][j];
        if (MODE == 0) {
          float rv = fmaxf(v, 0.f);
          ((u16*)Cout)[(size_t)(offE + gm) * N + gn] = f2bf(rv * rv);
        } else {
          int tok = permE[gm];
          ((float*)Cout)[(size_t)tok * N + gn] = Xadd[(size_t)tok * N + gn] + v;
        }
      }
    }
}

// ---- router: inline rms + fp32 logits + per-token stats
__global__ __launch_bounds__(64) void router_k(const float* __restrict__ xnew, const float* __restrict__ Wr,
                                               int* __restrict__ eidx, int* __restrict__ cnt,
                                               float* __restrict__ ts) {
  int t = blockIdx.x, lane = threadIdx.x;
  const float* h = xnew + (size_t)t * CDIM;
  float a0 = 0, a1 = 0, a2 = 0, a3 = 0, ss = 0;
  for (int i = lane; i < CDIM; i += 64) {
    float hv = h[i];
    ss += hv * hv;
    float4 wr = ((const float4*)Wr)[i];
    a0 += hv * wr.x; a1 += hv * wr.y; a2 += hv * wr.z; a3 += hv * wr.w;
  }
  for (int off = 32; off >= 1; off >>= 1) {
    a0 += __shfl_xor(a0, off); a1 += __shfl_xor(a1, off);
    a2 += __shfl_xor(a2, off); a3 += __shfl_xor(a3, off);
    ss += __shfl_xor(ss, off);
  }
  if (lane == 0) {
    float rs = 1.0f / sqrtf(ss * (1.f / CDIM) + EPS_RMS);
    float l[4] = {a0 * rs, a1 * rs, a2 * rs, a3 * rs};
    int am = 0; float mx = l[0];
    for (int e = 1; e < 4; ++e) if (l[e] > mx) { mx = l[e]; am = e; }
    float p[4], sum = 0;
    for (int e = 0; e < 4; ++e) { p[e] = __expf(l[e] - mx); sum += p[e]; }
    float lse = mx + logf(sum);
    float H = 0;
    for (int e = 0; e < 4; ++e) {
      float pr = p[e] / sum;
      H -= pr * logf(pr + 1e-9f);
      ts[t * 8 + e] = pr;
    }
    ts[t * 8 + 4] = H;
    ts[t * 8 + 5] = lse * lse;
    atomicAdd(&cnt[am], 1);
    eidx[t] = am;
  }
}

// ---- deterministic stats reduce + finalize (fp32 out)
__global__ __launch_bounds__(256) void reduce_k(const float* __restrict__ ts, const int* __restrict__ cnt,
                                                int* __restrict__ offs, int* __restrict__ cursor,
                                                float* __restrict__ outs) {
  __shared__ float buf[6][256];
  int tid = threadIdx.x;
  float s[6] = {0, 0, 0, 0, 0, 0};
  for (int t = tid; t < NTOK; t += 256)
    for (int k = 0; k < 6; ++k) s[k] += ts[t * 8 + k];
  for (int k = 0; k < 6; ++k) buf[k][tid] = s[k];
  __syncthreads();
  for (int st = 128; st >= 1; st >>= 1) {
    if (tid < st)
      for (int k = 0; k < 6; ++k) buf[k][tid] += buf[k][tid + st];
    __syncthreads();
  }
  if (tid == 0) {
    int o = 0;
    for (int e = 0; e < 4; ++e) { offs[e] = o; o += cnt[e]; cursor[e] = 0; }
    float aux = 0;
    for (int e = 0; e < 4; ++e)
      aux += ((float)cnt[e] * (1.f / NTOK)) * (buf[e][0] * (1.f / NTOK));
    outs[0] = 4.f * aux;
    outs[1] = buf[5][0] * (1.f / NTOK);
    outs[2] = (buf[4][0] * (1.f / NTOK)) / logf(4.f);
    for (int e = 0; e < 4; ++e) outs[3 + e] = (float)cnt[e] * (1.f / NTOK);
  }
}

__global__ __launch_bounds__(256) void scatter_k(const int* __restrict__ eidx, const int* __restrict__ offs,
                                                 int* __restrict__ cursor, int* __restrict__ perm) {
  int t = blockIdx.x * 256 + threadIdx.x;
  if (t >= NTOK) return;
  int e = eidx[t];
  int pos = atomicAdd(&cursor[e], 1);
  perm[offs[e] + pos] = t;
}

extern "C" void kernel_launch(void* const* d_in, const int* in_sizes, int n_in,
                              void* d_out, int out_size, void* d_ws, size_t ws_size,
                              hipStream_t stream) {
  (void)in_sizes; (void)n_in; (void)out_size; (void)ws_size;
  const float* x   = (const float*)d_in[0];
  const float* Wq  = (const float*)d_in[1];
  const float* Wk  = (const float*)d_in[2];
  const float* Wv  = (const float*)d_in[3];
  const float* Wo  = (const float*)d_in[4];
  const float* Wr  = (const float*)d_in[5];
  const float* Wfc = (const float*)d_in[6];
  const float* Wpr = (const float*)d_in[7];
  float* out = (float*)d_out;
  uint8_t* ws = (uint8_t*)d_ws;

  size_t off = 0;
  auto alloc = [&](size_t b) { size_t p = off; off += (b + 255) & ~(size_t)255; return p; };
  float* ropeC = (float*)(ws + alloc(262144));
  float* ropeS = (float*)(ws + alloc(262144));
  float* ts    = (float*)(ws + alloc(131072));
  int* eidx = (int*)(ws + alloc(16384));
  int* perm = (int*)(ws + alloc(16384));
  uint8_t* stats = ws + alloc(256);
  int* cnt = (int*)stats;
  int* offsv = cnt + 4;
  int* cursor = cnt + 8;
  u16* wqh = (u16*)(ws + alloc(2097152));
  u16* wql = (u16*)(ws + alloc(2097152));
  u16* wkh = (u16*)(ws + alloc(2097152));
  u16* wkl = (u16*)(ws + alloc(2097152));
  u16* wvh = (u16*)(ws + alloc(2097152));
  u16* wvl = (u16*)(ws + alloc(2097152));
  u16* woh = (u16*)(ws + alloc(2097152));
  u16* wol = (u16*)(ws + alloc(2097152));
  u16* wfcT = (u16*)(ws + alloc(33554432));       // reused for wprT after fc
  u16* h1h = (u16*)(ws + alloc(8388608));         // -> xnew (fp32, spans h1h+h1l)
  u16* h1l = (u16*)(ws + alloc(8388608));
  u16* qh = (u16*)(ws + alloc(8388608));          // -> hid (bf16, spans qh..kl)
  u16* ql = (u16*)(ws + alloc(8388608));
  u16* kh = (u16*)(ws + alloc(8388608));
  u16* kl = (u16*)(ws + alloc(8388608));
  u16* vh = (u16*)(ws + alloc(8388608));          // -> yh
  u16* vl = (u16*)(ws + alloc(8388608));          // -> yl
  u16* vth = (u16*)(ws + alloc(8388608));         // -> h2b
  u16* vtl = (u16*)(ws + alloc(8388608));
  // lifetime-disjoint aliases:
  float* xnew = (float*)h1h;   // h1h/h1l dead after V-GEMM; written by Wo-GEMM
  u16* yh = vh;                // vh/vl dead after vtrans; written by attn
  u16* yl = vl;
  u16* h2b = vth;              // vth/vtl dead after attn
  u16* hid = qh;               // qh+ql+kh+kl = 33.55MB, dead after attn
  u16* wprT = wfcT;            // wfcT dead after fc GEMM

  hipMemsetAsync(stats, 0, 256, stream);
  rope_table_k<<<256, 256, 0, stream>>>(ropeC, ropeS);
  wsplit_k<<<dim3(32, 32), 256, 0, stream>>>(Wq, wqh, wql, 1024, 1024);
  wsplit_k<<<dim3(32, 32), 256, 0, stream>>>(Wk, wkh, wkl, 1024, 1024);
  wsplit_k<<<dim3(32, 32), 256, 0, stream>>>(Wv, wvh, wvl, 1024, 1024);
  wsplit_k<<<dim3(32, 32), 256, 0, stream>>>(Wo, woh, wol, 1024, 1024);
  wcast_k<<<dim3(128, 32, 4), 256, 0, stream>>>(Wfc, wfcT, 1024, 4096);
  rmsnorm_split_k<<<NTOK, 256, 0, stream>>>(x, h1h, h1l);

  gemm_sp_k<0><<<dim3(8, 32), 256, 0, stream>>>(h1h, h1l, wqh, wql, nullptr, nullptr, qh, ql, ropeC, ropeS);
  gemm_sp_k<0><<<dim3(8, 32), 256, 0, stream>>>(h1h, h1l, wkh, wkl, nullptr, nullptr, kh, kl, ropeC, ropeS);
  gemm_sp_k<1><<<dim3(8, 32), 256, 0, stream>>>(h1h, h1l, wvh, wvl, nullptr, nullptr, vh, vl, nullptr, nullptr);
  vtrans_k<<<dim3(32, 32, 2), 256, 0, stream>>>(vh, vl, vth, vtl);
  attn_k<<<dim3(64, 32), 64, 0, stream>>>(qh, ql, kh, kl, vth, vtl, yh, yl);
  gemm_sp_k<2><<<dim3(8, 32), 256, 0, stream>>>(yh, yl, woh, wol, x, xnew, nullptr, nullptr, nullptr, nullptr);

  rmsnorm_b_k<<<NTOK, 256, 0, stream>>>(xnew, h2b);
  router_k<<<NTOK, 64, 0, stream>>>(xnew, Wr, eidx, cnt, ts);
  reduce_k<<<1, 256, 0, stream>>>(ts, cnt, offsv, cursor, out + 4194304);
  scatter_k<<<16, 256, 0, stream>>>(eidx, offsv, cursor, perm);
  gemm_moe_k<0><<<dim3(32, 32, 4), 256, 0, stream>>>(h2b, wfcT, hid, nullptr, perm, cnt, offsv);
  wcast_k<<<dim3(32, 128, 4), 256, 0, stream>>>(Wpr, wprT, 4096, 1024);
  gemm_moe_k<1><<<dim3(8, 32, 4), 256, 0, stream>>>(hid, wprT, out, xnew, perm, cnt, offsv);
}

// Round 7
// 947.224 us; speedup vs baseline: 1.1206x; 1.0768x over previous
//
#include <hip/hip_runtime.h>
#include <stdint.h>

typedef unsigned short u16;
typedef __attribute__((ext_vector_type(8))) __bf16 bf16x8;
typedef __attribute__((ext_vector_type(4))) float f32x4;

#define T_SEQ 2048
#define CDIM 1024
#define NH 16
#define HD 64
#define NTOK 4096
#define EPS_RMS 1.1920929e-07f
#define LDKs 72

__device__ __forceinline__ u16 f2bf(float x) {
  union { float f; uint32_t u; } v; v.f = x;
  uint32_t r = v.u + 0x7fffu + ((v.u >> 16) & 1u);
  return (u16)(r >> 16);
}
__device__ __forceinline__ float bf2f(u16 h) {
  union { uint32_t u; float f; } v; v.u = ((uint32_t)h) << 16; return v.f;
}
__device__ __forceinline__ bf16x8 ld8(const u16* p) {
  uint4 q = *(const uint4*)p;
  return __builtin_bit_cast(bf16x8, q);
}
#define MFMA16(a, b, c) __builtin_amdgcn_mfma_f32_16x16x32_bf16((a), (b), (c), 0, 0, 0)
// wave-local LDS fence (P_s is wave-private; no cross-wave barrier needed)
#define WAVE_LDS_FENCE() do { asm volatile("s_waitcnt lgkmcnt(0)" ::: "memory"); __builtin_amdgcn_wave_barrier(); } while (0)

// ---- rope table
__global__ __launch_bounds__(256) void rope_table_k(float* __restrict__ cosT, float* __restrict__ sinT) {
  int idx = blockIdx.x * 256 + threadIdx.x;   // T*32
  int t = idx >> 5, d = idx & 31;
  float inv = 1.0f / powf(10000.0f, (float)(2 * d) / 64.0f);
  float a = (float)t * inv;
  cosT[idx] = cosf(a);
  sinT[idx] = sinf(a);
}

// ---- transpose + SPLIT fp32 (R x Cc) -> bf16 hi + lo (Cc x R)
__global__ __launch_bounds__(256) void wsplit_k(const float* __restrict__ in,
                                                u16* __restrict__ ohi, u16* __restrict__ olo,
                                                int R, int Cc) {
  __shared__ float tile[32][33];
  int c0 = blockIdx.x * 32, r0 = blockIdx.y * 32;
  int tx = threadIdx.x & 31, ty = threadIdx.x >> 5;
  for (int i = ty; i < 32; i += 8)
    tile[i][tx] = in[(size_t)(r0 + i) * Cc + (c0 + tx)];
  __syncthreads();
  for (int i = ty; i < 32; i += 8) {
    float v = tile[tx][i];
    u16 h = f2bf(v);
    ohi[(size_t)(c0 + i) * R + (r0 + tx)] = h;
    olo[(size_t)(c0 + i) * R + (r0 + tx)] = f2bf(v - bf2f(h));
  }
}

// ---- transpose + cast fp32 (R x Cc) -> bf16 (Cc x R), z-batched
__global__ __launch_bounds__(256) void wcast_k(const float* __restrict__ in,
                                               u16* __restrict__ out, int R, int Cc) {
  size_t zoff = (size_t)blockIdx.z * (size_t)R * (size_t)Cc;
  in += zoff; out += zoff;
  __shared__ float tile[32][33];
  int c0 = blockIdx.x * 32, r0 = blockIdx.y * 32;
  int tx = threadIdx.x & 31, ty = threadIdx.x >> 5;
  for (int i = ty; i < 32; i += 8)
    tile[i][tx] = in[(size_t)(r0 + i) * Cc + (c0 + tx)];
  __syncthreads();
  for (int i = ty; i < 32; i += 8)
    out[(size_t)(c0 + i) * R + (r0 + tx)] = f2bf(tile[tx][i]);
}

// ---- rmsnorm over C=1024, split hi/lo bf16 out
__global__ __launch_bounds__(256) void rmsnorm_split_k(const float* __restrict__ x,
                                                       u16* __restrict__ hh, u16* __restrict__ hl) {
  int row = blockIdx.x;
  const float* xr = x + (size_t)row * CDIM;
  int tid = threadIdx.x;
  float v[4]; float s = 0.f;
  for (int i = 0; i < 4; ++i) { v[i] = xr[tid + 256 * i]; s += v[i] * v[i]; }
  for (int off = 32; off >= 1; off >>= 1) s += __shfl_xor(s, off);
  __shared__ float red[4];
  int w = tid >> 6, lane = tid & 63;
  if (lane == 0) red[w] = s;
  __syncthreads();
  s = red[0] + red[1] + red[2] + red[3];
  float rs = 1.0f / sqrtf(s * (1.f / CDIM) + EPS_RMS);
  for (int i = 0; i < 4; ++i) {
    float o = v[i] * rs;
    u16 h = f2bf(o);
    hh[(size_t)row * CDIM + tid + 256 * i] = h;
    hl[(size_t)row * CDIM + tid + 256 * i] = f2bf(o - bf2f(h));
  }
}

// ---- rmsnorm bf16 out
__global__ __launch_bounds__(256) void rmsnorm_b_k(const float* __restrict__ x, u16* __restrict__ hb) {
  int row = blockIdx.x;
  const float* xr = x + (size_t)row * CDIM;
  int tid = threadIdx.x;
  float v[4]; float s = 0.f;
  for (int i = 0; i < 4; ++i) { v[i] = xr[tid + 256 * i]; s += v[i] * v[i]; }
  for (int off = 32; off >= 1; off >>= 1) s += __shfl_xor(s, off);
  __shared__ float red[4];
  int w = tid >> 6, lane = tid & 63;
  if (lane == 0) red[w] = s;
  __syncthreads();
  s = red[0] + red[1] + red[2] + red[3];
  float rs = 1.0f / sqrtf(s * (1.f / CDIM) + EPS_RMS);
  for (int i = 0; i < 4; ++i) hb[(size_t)row * CDIM + tid + 256 * i] = f2bf(v[i] * rs);
}

// ---- split GEMM, all operands PRE-SPLIT bf16: C = A(M x K) * B^T (N x K)
// 3-product Ootomo accumulate. EPI 0: per-head RMS+rope -> (b,h,t,d) hi/lo.
// EPI 1: split store (b,t,c). EPI 2: fp32 out = Xadd + acc.
template <int EPI>
__global__ __launch_bounds__(256) void gemm_sp_k(const u16* __restrict__ Ahp, const u16* __restrict__ Alp,
                                                 const u16* __restrict__ Bhp, const u16* __restrict__ Blp,
                                                 const float* __restrict__ Xadd, float* __restrict__ outF,
                                                 u16* __restrict__ outH, u16* __restrict__ outL,
                                                 const float* __restrict__ cosT, const float* __restrict__ sinT) {
  const int N = CDIM, K = CDIM;
  __shared__ __align__(16) u16 Ah[128][LDKs];
  __shared__ __align__(16) u16 Al[128][LDKs];
  __shared__ __align__(16) u16 Bh[128][LDKs];
  __shared__ __align__(16) u16 Bl[128][LDKs];
  int m0 = blockIdx.y * 128, n0 = blockIdx.x * 128;
  int tid = threadIdx.x, lane = tid & 63, w = tid >> 6;
  int wr = w >> 1, wc = w & 1;
  int fr = lane & 15, fq = lane >> 4, kof = fq * 8;
  int rB = tid >> 3, colB = (tid & 7) * 8;
  f32x4 acc[4][4] = {};
  for (int kt = 0; kt < K; kt += 64) {
    #pragma unroll
    for (int i = 0; i < 4; ++i) {
      int r = rB + i * 32;
      *(uint4*)&Ah[r][colB] = *(const uint4*)(Ahp + (size_t)(m0 + r) * K + kt + colB);
      *(uint4*)&Al[r][colB] = *(const uint4*)(Alp + (size_t)(m0 + r) * K + kt + colB);
      *(uint4*)&Bh[r][colB] = *(const uint4*)(Bhp + (size_t)(n0 + r) * K + kt + colB);
      *(uint4*)&Bl[r][colB] = *(const uint4*)(Blp + (size_t)(n0 + r) * K + kt + colB);
    }
    __syncthreads();
    #pragma unroll
    for (int ks = 0; ks < 2; ++ks) {
      int kk = ks * 32 + kof;
      bf16x8 ah[4], al[4], bh4[4], bl4[4];
      #pragma unroll
      for (int i = 0; i < 4; ++i) {
        ah[i] = ld8(&Ah[wr * 64 + i * 16 + fr][kk]);
        al[i] = ld8(&Al[wr * 64 + i * 16 + fr][kk]);
      }
      #pragma unroll
      for (int j = 0; j < 4; ++j) {
        bh4[j] = ld8(&Bh[wc * 64 + j * 16 + fr][kk]);
        bl4[j] = ld8(&Bl[wc * 64 + j * 16 + fr][kk]);
      }
      #pragma unroll
      for (int i = 0; i < 4; ++i)
        #pragma unroll
        for (int j = 0; j < 4; ++j) {
          acc[i][j] = MFMA16(al[i], bh4[j], acc[i][j]);
          acc[i][j] = MFMA16(ah[i], bl4[j], acc[i][j]);
          acc[i][j] = MFMA16(ah[i], bh4[j], acc[i][j]);
        }
    }
    __syncthreads();
  }
  if (EPI == 0) {
    int h = (n0 + wc * 64) >> 6;
    #pragma unroll
    for (int i = 0; i < 4; ++i) {
      #pragma unroll
      for (int j = 0; j < 4; ++j) {
        int row = m0 + wr * 64 + i * 16 + fq * 4 + j;
        float v0 = acc[i][0][j], v1 = acc[i][1][j], v2 = acc[i][2][j], v3 = acc[i][3][j];
        float ss = v0 * v0 + v1 * v1 + v2 * v2 + v3 * v3;
        ss += __shfl_xor(ss, 1); ss += __shfl_xor(ss, 2);
        ss += __shfl_xor(ss, 4); ss += __shfl_xor(ss, 8);
        float rs = 1.0f / sqrtf(ss * (1.f / HD) + EPS_RMS);
        float x0 = v0 * rs, x1 = v1 * rs, x2 = v2 * rs, x3 = v3 * rs;
        int t = row & (T_SEQ - 1), b = row >> 11;
        float c0 = cosT[t * 32 + fr],      s0 = sinT[t * 32 + fr];
        float c1 = cosT[t * 32 + fr + 16], s1 = sinT[t * 32 + fr + 16];
        float o0 = x0 * c0 + x2 * s0;
        float o1 = x1 * c1 + x3 * s1;
        float o2 = x2 * c0 - x0 * s0;
        float o3 = x3 * c1 - x1 * s1;
        size_t base = ((size_t)(b * NH + h) * T_SEQ + t) * HD + fr;
        u16 hh;
        hh = f2bf(o0); outH[base]      = hh; outL[base]      = f2bf(o0 - bf2f(hh));
        hh = f2bf(o1); outH[base + 16] = hh; outL[base + 16] = f2bf(o1 - bf2f(hh));
        hh = f2bf(o2); outH[base + 32] = hh; outL[base + 32] = f2bf(o2 - bf2f(hh));
        hh = f2bf(o3); outH[base + 48] = hh; outL[base + 48] = f2bf(o3 - bf2f(hh));
      }
    }
  } else {
    #pragma unroll
    for (int i = 0; i < 4; ++i)
      #pragma unroll
      for (int j = 0; j < 4; ++j) {
        int row = m0 + wr * 64 + i * 16 + fq * 4 + j;
        #pragma unroll
        for (int jf = 0; jf < 4; ++jf) {
          int gn = n0 + wc * 64 + jf * 16 + fr;
          float v = acc[i][jf][j];
          if (EPI == 1) {
            u16 hh = f2bf(v);
            outH[(size_t)row * CDIM + gn] = hh;
            outL[(size_t)row * CDIM + gn] = f2bf(v - bf2f(hh));
          } else {
            outF[(size_t)row * CDIM + gn] = Xadd[(size_t)row * CDIM + gn] + v;
          }
        }
      }
  }
}

// ---- transpose v (bf16): (b,t,h,d) -> (b,h,d,t); z selects hi/lo
__global__ __launch_bounds__(256) void vtrans_k(const u16* __restrict__ vhp, const u16* __restrict__ vlp,
                                                u16* __restrict__ vthp, u16* __restrict__ vtlp) {
  const u16* src = blockIdx.z ? vlp : vhp;
  u16* dst = blockIdx.z ? vtlp : vthp;
  __shared__ u16 t_[64][65];
  int bh = blockIdx.y, b = bh >> 4, h = bh & 15;
  int t0 = blockIdx.x * 64;
  const u16* in = src + ((size_t)b * T_SEQ) * CDIM + (size_t)h * HD;
  u16* out = dst + (size_t)bh * HD * T_SEQ;
  int tx = threadIdx.x & 63, ty = threadIdx.x >> 6;
  for (int i = ty; i < 64; i += 4) t_[i][tx] = in[(size_t)(t0 + i) * CDIM + tx];
  __syncthreads();
  for (int i = ty; i < 64; i += 4) out[(size_t)i * T_SEQ + t0 + tx] = t_[tx][i];
}

// ---- flash attention (split precision), 4 independent waves per block.
// wave w of block p owns q-tile qt = p + 16*w  (strided -> balanced CU load,
// 2 blocks/CU held resident for the whole kernel => 2 waves/SIMD overlap).
// P_s is per-wave; no block barriers (waves have different trip counts).
__global__ __launch_bounds__(256) void attn_k(const u16* __restrict__ qhp, const u16* __restrict__ qlp,
                                              const u16* __restrict__ khp, const u16* __restrict__ klp,
                                              const u16* __restrict__ vth, const u16* __restrict__ vtl,
                                              u16* __restrict__ yh, u16* __restrict__ yl) {
  int wv = threadIdx.x >> 6, lane = threadIdx.x & 63;
  int bh = blockIdx.y;
  int qt = blockIdx.x + 16 * wv;   // 0..63
  size_t o1 = (size_t)bh * T_SEQ * HD;
  const u16* Qh = qhp + o1; const u16* Ql = qlp + o1;
  const u16* Kh = khp + o1; const u16* Kl = klp + o1;
  const u16* Vh = vth + o1; const u16* Vl = vtl + o1;
  int q0 = qt * 32;
  int l15 = lane & 15, lg = lane >> 4, kof = lg * 8;
  bf16x8 aqh[2][2], aql[2][2];
  for (int m = 0; m < 2; ++m)
    for (int kc = 0; kc < 2; ++kc) {
      size_t p = (size_t)(q0 + 16 * m + l15) * HD + kc * 32 + kof;
      aqh[m][kc] = ld8(Qh + p);
      aql[m][kc] = ld8(Ql + p);
    }
  f32x4 o[2][4] = {};
  float mrow[2][4], lrow[2][4];
  for (int m = 0; m < 2; ++m)
    for (int r = 0; r < 4; ++r) { mrow[m][r] = -1e30f; lrow[m][r] = 0.f; }
  __shared__ __align__(16) float P_s[4][32][36];
  float (* __restrict__ Pw)[36] = P_s[wv];
  for (int j = 0; j <= qt; ++j) {
    int t0 = j * 32;
    bf16x8 bkh[2][2], bkl[2][2];
    for (int n = 0; n < 2; ++n)
      for (int kc = 0; kc < 2; ++kc) {
        size_t p = (size_t)(t0 + 16 * n + l15) * HD + kc * 32 + kof;
        bkh[n][kc] = ld8(Kh + p);
        bkl[n][kc] = ld8(Kl + p);
      }
    f32x4 sfr[2][2];
    for (int m = 0; m < 2; ++m)
      for (int n = 0; n < 2; ++n) {
        f32x4 z = {};
        for (int kc = 0; kc < 2; ++kc) {
          z = MFMA16(aql[m][kc], bkh[n][kc], z);
          z = MFMA16(aqh[m][kc], bkl[n][kc], z);
          z = MFMA16(aqh[m][kc], bkh[n][kc], z);
        }
        sfr[m][n] = z;
      }
    for (int m = 0; m < 2; ++m) {
      for (int r = 0; r < 4; ++r) {
        int grow = q0 + 16 * m + lg * 4 + r;
        float v0 = sfr[m][0][r] * 0.125f;
        float v1 = sfr[m][1][r] * 0.125f;
        if (t0 + l15 > grow) v0 = -1e30f;
        if (t0 + 16 + l15 > grow) v1 = -1e30f;
        float mx = fmaxf(v0, v1);
        for (int off = 8; off >= 1; off >>= 1) mx = fmaxf(mx, __shfl_xor(mx, off));
        float mnew = fmaxf(mrow[m][r], mx);
        float alpha = __expf(mrow[m][r] - mnew);
        float p0 = __expf(v0 - mnew);
        float p1 = __expf(v1 - mnew);
        float ps = p0 + p1;
        for (int off = 8; off >= 1; off >>= 1) ps += __shfl_xor(ps, off);
        mrow[m][r] = mnew;
        lrow[m][r] = lrow[m][r] * alpha + ps;
        for (int dt = 0; dt < 4; ++dt) o[m][dt][r] *= alpha;
        Pw[16 * m + lg * 4 + r][l15] = p0;
        Pw[16 * m + lg * 4 + r][l15 + 16] = p1;
      }
    }
    WAVE_LDS_FENCE();
    bf16x8 ph[2], pl[2];
    for (int m = 0; m < 2; ++m)
      for (int jj = 0; jj < 8; ++jj) {
        float vv = Pw[16 * m + l15][kof + jj];
        u16 hv = f2bf(vv);
        ph[m][jj] = __builtin_bit_cast(__bf16, hv);
        pl[m][jj] = __builtin_bit_cast(__bf16, f2bf(vv - bf2f(hv)));
      }
    WAVE_LDS_FENCE();
    for (int m = 0; m < 2; ++m)
      for (int dt = 0; dt < 4; ++dt) {
        size_t vp = (size_t)(dt * 16 + l15) * T_SEQ + t0 + kof;
        bf16x8 bvh = ld8(Vh + vp);
        bf16x8 bvl = ld8(Vl + vp);
        o[m][dt] = MFMA16(pl[m], bvh, o[m][dt]);
        o[m][dt] = MFMA16(ph[m], bvl, o[m][dt]);
        o[m][dt] = MFMA16(ph[m], bvh, o[m][dt]);
      }
  }
  int b = bh >> 4, h = bh & 15;
  for (int m = 0; m < 2; ++m)
    for (int r = 0; r < 4; ++r) {
      float inv = 1.f / lrow[m][r];
      int grow = q0 + 16 * m + lg * 4 + r;
      for (int dt = 0; dt < 4; ++dt) {
        size_t idx = ((size_t)b * T_SEQ + grow) * CDIM + h * HD + dt * 16 + l15;
        float vv = o[m][dt][r] * inv;
        u16 hh = f2bf(vv);
        yh[idx] = hh;
        yl[idx] = f2bf(vv - bf2f(hh));
      }
    }
}

// ---- MoE GEMM: A bf16, B bf16 pre-cast (NxK k-contig per expert).
// MODE 0: fc (gather rows via perm, relu^2 -> bf16 hid). MODE 1: proj (scatter + residual -> fp32 out)
template <int MODE>
__global__ __launch_bounds__(256) void gemm_moe_k(const u16* __restrict__ Abf, const u16* __restrict__ BT,
                                                  void* __restrict__ Cout, const float* __restrict__ Xadd,
                                                  const int* __restrict__ perm, const int* __restrict__ cnt,
                                                  const int* __restrict__ offs) {
  const int N = (MODE == 0) ? 4096 : 1024;
  const int K = (MODE == 0) ? 1024 : 4096;
  int e = blockIdx.z;
  int Me = cnt[e];
  int m0 = blockIdx.y * 128;
  if (m0 >= Me) return;
  int n0 = blockIdx.x * 128;
  int offE = offs[e];
  const int* permE = perm + offE;
  const u16* BTe = BT + (size_t)e * (size_t)N * (size_t)K;
  __shared__ __align__(16) u16 As[128][LDKs];
  __shared__ __align__(16) u16 Bs[128][LDKs];
  int tid = threadIdx.x, lane = tid & 63, w = tid >> 6;
  int wr = w >> 1, wc = w & 1;
  int fr = lane & 15, fq = lane >> 4, kof = fq * 8;
  int rB = tid >> 3, colB = (tid & 7) * 8;
  const u16* asrc[4];
  #pragma unroll
  for (int i = 0; i < 4; ++i) {
    int gr = m0 + rB + i * 32;
    if (MODE == 0) {
      int tok = permE[gr < Me ? gr : 0];
      asrc[i] = Abf + (size_t)tok * K;
    } else {
      if (gr >= Me) gr = Me - 1;
      asrc[i] = Abf + (size_t)(offE + gr) * K;
    }
  }
  f32x4 acc[4][4] = {};
  for (int kt = 0; kt < K; kt += 64) {
    #pragma unroll
    for (int i = 0; i < 4; ++i) {
      int r = rB + i * 32;
      *(uint4*)&As[r][colB] = *(const uint4*)(asrc[i] + kt + colB);
      *(uint4*)&Bs[r][colB] = *(const uint4*)(BTe + (size_t)(n0 + r) * K + kt + colB);
    }
    __syncthreads();
    #pragma unroll
    for (int ks = 0; ks < 2; ++ks) {
      int kk = ks * 32 + kof;
      bf16x8 af[4], bfr[4];
      #pragma unroll
      for (int i = 0; i < 4; ++i) af[i] = ld8(&As[wr * 64 + i * 16 + fr][kk]);
      #pragma unroll
      for (int j = 0; j < 4; ++j) bfr[j] = ld8(&Bs[wc * 64 + j * 16 + fr][kk]);
      #pragma unroll
      for (int i = 0; i < 4; ++i)
        #pragma unroll
        for (int j = 0; j < 4; ++j)
          acc[i][j] = MFMA16(af[i], bfr[j], acc[i][j]);
    }
    __syncthreads();
  }
  #pragma unroll
  for (int i = 0; i < 4; ++i)
    #pragma unroll
    for (int j = 0; j < 4; ++j) {
      int lrow = wr * 64 + i * 16 + fq * 4 + j;
      int gm = m0 + lrow;
      if (gm >= Me) continue;
      #pragma unroll
      for (int jf = 0; jf < 4; ++jf) {
        int gn = n0 + wc * 64 + jf * 16 + fr;
        float v = acc[i][jf][j];
        if (MODE == 0) {
          float rv = fmaxf(v, 0.f);
          ((u16*)Cout)[(size_t)(offE + gm) * N + gn] = f2bf(rv * rv);
        } else {
          int tok = permE[gm];
          ((float*)Cout)[(size_t)tok * N + gn] = Xadd[(size_t)tok * N + gn] + v;
        }
      }
    }
}

// ---- router: inline rms + fp32 logits + per-token stats
__global__ __launch_bounds__(64) void router_k(const float* __restrict__ xnew, const float* __restrict__ Wr,
                                               int* __restrict__ eidx, int* __restrict__ cnt,
                                               float* __restrict__ ts) {
  int t = blockIdx.x, lane = threadIdx.x;
  const float* h = xnew + (size_t)t * CDIM;
  float a0 = 0, a1 = 0, a2 = 0, a3 = 0, ss = 0;
  for (int i = lane; i < CDIM; i += 64) {
    float hv = h[i];
    ss += hv * hv;
    float4 wr = ((const float4*)Wr)[i];
    a0 += hv * wr.x; a1 += hv * wr.y; a2 += hv * wr.z; a3 += hv * wr.w;
  }
  for (int off = 32; off >= 1; off >>= 1) {
    a0 += __shfl_xor(a0, off); a1 += __shfl_xor(a1, off);
    a2 += __shfl_xor(a2, off); a3 += __shfl_xor(a3, off);
    ss += __shfl_xor(ss, off);
  }
  if (lane == 0) {
    float rs = 1.0f / sqrtf(ss * (1.f / CDIM) + EPS_RMS);
    float l[4] = {a0 * rs, a1 * rs, a2 * rs, a3 * rs};
    int am = 0; float mx = l[0];
    for (int e = 1; e < 4; ++e) if (l[e] > mx) { mx = l[e]; am = e; }
    float p[4], sum = 0;
    for (int e = 0; e < 4; ++e) { p[e] = __expf(l[e] - mx); sum += p[e]; }
    float lse = mx + logf(sum);
    float H = 0;
    for (int e = 0; e < 4; ++e) {
      float pr = p[e] / sum;
      H -= pr * logf(pr + 1e-9f);
      ts[t * 8 + e] = pr;
    }
    ts[t * 8 + 4] = H;
    ts[t * 8 + 5] = lse * lse;
    atomicAdd(&cnt[am], 1);
    eidx[t] = am;
  }
}

// ---- deterministic stats reduce + finalize (fp32 out)
__global__ __launch_bounds__(256) void reduce_k(const float* __restrict__ ts, const int* __restrict__ cnt,
                                                int* __restrict__ offs, int* __restrict__ cursor,
                                                float* __restrict__ outs) {
  __shared__ float buf[6][256];
  int tid = threadIdx.x;
  float s[6] = {0, 0, 0, 0, 0, 0};
  for (int t = tid; t < NTOK; t += 256)
    for (int k = 0; k < 6; ++k) s[k] += ts[t * 8 + k];
  for (int k = 0; k < 6; ++k) buf[k][tid] = s[k];
  __syncthreads();
  for (int st = 128; st >= 1; st >>= 1) {
    if (tid < st)
      for (int k = 0; k < 6; ++k) buf[k][tid] += buf[k][tid + st];
    __syncthreads();
  }
  if (tid == 0) {
    int o = 0;
    for (int e = 0; e < 4; ++e) { offs[e] = o; o += cnt[e]; cursor[e] = 0; }
    float aux = 0;
    for (int e = 0; e < 4; ++e)
      aux += ((float)cnt[e] * (1.f / NTOK)) * (buf[e][0] * (1.f / NTOK));
    outs[0] = 4.f * aux;
    outs[1] = buf[5][0] * (1.f / NTOK);
    outs[2] = (buf[4][0] * (1.f / NTOK)) / logf(4.f);
    for (int e = 0; e < 4; ++e) outs[3 + e] = (float)cnt[e] * (1.f / NTOK);
  }
}

__global__ __launch_bounds__(256) void scatter_k(const int* __restrict__ eidx, const int* __restrict__ offs,
                                                 int* __restrict__ cursor, int* __restrict__ perm) {
  int t = blockIdx.x * 256 + threadIdx.x;
  if (t >= NTOK) return;
  int e = eidx[t];
  int pos = atomicAdd(&cursor[e], 1);
  perm[offs[e] + pos] = t;
}

extern "C" void kernel_launch(void* const* d_in, const int* in_sizes, int n_in,
                              void* d_out, int out_size, void* d_ws, size_t ws_size,
                              hipStream_t stream) {
  (void)in_sizes; (void)n_in; (void)out_size; (void)ws_size;
  const float* x   = (const float*)d_in[0];
  const float* Wq  = (const float*)d_in[1];
  const float* Wk  = (const float*)d_in[2];
  const float* Wv  = (const float*)d_in[3];
  const float* Wo  = (const float*)d_in[4];
  const float* Wr  = (const float*)d_in[5];
  const float* Wfc = (const float*)d_in[6];
  const float* Wpr = (const float*)d_in[7];
  float* out = (float*)d_out;
  uint8_t* ws = (uint8_t*)d_ws;

  size_t off = 0;
  auto alloc = [&](size_t b) { size_t p = off; off += (b + 255) & ~(size_t)255; return p; };
  float* ropeC = (float*)(ws + alloc(262144));
  float* ropeS = (float*)(ws + alloc(262144));
  float* ts    = (float*)(ws + alloc(131072));
  int* eidx = (int*)(ws + alloc(16384));
  int* perm = (int*)(ws + alloc(16384));
  uint8_t* stats = ws + alloc(256);
  int* cnt = (int*)stats;
  int* offsv = cnt + 4;
  int* cursor = cnt + 8;
  u16* wqh = (u16*)(ws + alloc(2097152));
  u16* wql = (u16*)(ws + alloc(2097152));
  u16* wkh = (u16*)(ws + alloc(2097152));
  u16* wkl = (u16*)(ws + alloc(2097152));
  u16* wvh = (u16*)(ws + alloc(2097152));
  u16* wvl = (u16*)(ws + alloc(2097152));
  u16* woh = (u16*)(ws + alloc(2097152));
  u16* wol = (u16*)(ws + alloc(2097152));
  u16* wfcT = (u16*)(ws + alloc(33554432));       // reused for wprT after fc
  u16* h1h = (u16*)(ws + alloc(8388608));         // -> xnew (fp32, spans h1h+h1l)
  u16* h1l = (u16*)(ws + alloc(8388608));
  u16* qh = (u16*)(ws + alloc(8388608));          // -> hid (bf16, spans qh..kl)
  u16* ql = (u16*)(ws + alloc(8388608));
  u16* kh = (u16*)(ws + alloc(8388608));
  u16* kl = (u16*)(ws + alloc(8388608));
  u16* vh = (u16*)(ws + alloc(8388608));          // -> yh
  u16* vl = (u16*)(ws + alloc(8388608));          // -> yl
  u16* vth = (u16*)(ws + alloc(8388608));         // -> h2b
  u16* vtl = (u16*)(ws + alloc(8388608));
  // lifetime-disjoint aliases:
  float* xnew = (float*)h1h;   // h1h/h1l dead after V-GEMM; written by Wo-GEMM
  u16* yh = vh;                // vh/vl dead after vtrans; written by attn
  u16* yl = vl;
  u16* h2b = vth;              // vth/vtl dead after attn
  u16* hid = qh;               // qh+ql+kh+kl = 33.55MB, dead after attn
  u16* wprT = wfcT;            // wfcT dead after fc GEMM

  hipMemsetAsync(stats, 0, 256, stream);
  rope_table_k<<<256, 256, 0, stream>>>(ropeC, ropeS);
  wsplit_k<<<dim3(32, 32), 256, 0, stream>>>(Wq, wqh, wql, 1024, 1024);
  wsplit_k<<<dim3(32, 32), 256, 0, stream>>>(Wk, wkh, wkl, 1024, 1024);
  wsplit_k<<<dim3(32, 32), 256, 0, stream>>>(Wv, wvh, wvl, 1024, 1024);
  wsplit_k<<<dim3(32, 32), 256, 0, stream>>>(Wo, woh, wol, 1024, 1024);
  wcast_k<<<dim3(128, 32, 4), 256, 0, stream>>>(Wfc, wfcT, 1024, 4096);
  rmsnorm_split_k<<<NTOK, 256, 0, stream>>>(x, h1h, h1l);

  gemm_sp_k<0><<<dim3(8, 32), 256, 0, stream>>>(h1h, h1l, wqh, wql, nullptr, nullptr, qh, ql, ropeC, ropeS);
  gemm_sp_k<0><<<dim3(8, 32), 256, 0, stream>>>(h1h, h1l, wkh, wkl, nullptr, nullptr, kh, kl, ropeC, ropeS);
  gemm_sp_k<1><<<dim3(8, 32), 256, 0, stream>>>(h1h, h1l, wvh, wvl, nullptr, nullptr, vh, vl, nullptr, nullptr);
  vtrans_k<<<dim3(32, 32, 2), 256, 0, stream>>>(vh, vl, vth, vtl);
  attn_k<<<dim3(16, 32), 256, 0, stream>>>(qh, ql, kh, kl, vth, vtl, yh, yl);
  gemm_sp_k<2><<<dim3(8, 32), 256, 0, stream>>>(yh, yl, woh, wol, x, xnew, nullptr, nullptr, nullptr, nullptr);

  rmsnorm_b_k<<<NTOK, 256, 0, stream>>>(xnew, h2b);
  router_k<<<NTOK, 64, 0, stream>>>(xnew, Wr, eidx, cnt, ts);
  reduce_k<<<1, 256, 0, stream>>>(ts, cnt, offsv, cursor, out + 4194304);
  scatter_k<<<16, 256, 0, stream>>>(eidx, offsv, cursor, perm);
  gemm_moe_k<0><<<dim3(32, 32, 4), 256, 0, stream>>>(h2b, wfcT, hid, nullptr, perm, cnt, offsv);
  wcast_k<<<dim3(32, 128, 4), 256, 0, stream>>>(Wpr, wprT, 4096, 1024);
  gemm_moe_k<1><<<dim3(8, 32, 4), 256, 0, stream>>>(hid, wprT, out, xnew, perm, cnt, offsv);
}